// Round 1
// 114.903 us; speedup vs baseline: 1.0076x; 1.0076x over previous
//
#include <hip/hip_runtime.h>
#include <math.h>

// Problem constants (from reference setup_inputs)
#define BS 64      // batch
#define F  256     // features (K of the Gram matmul)
#define M  128     // columns  (M=N of the Gram matmul)
#define MF (M * F) // u16 elements per matrix in hT
#define NBP 1056   // blocks per mat: sum_a ceil((64-a)/2)

typedef unsigned short u16;
typedef _Float16 f16x8 __attribute__((ext_vector_type(8)));
typedef float    f32x16 __attribute__((ext_vector_type(16)));

// ---------------------------------------------------------------------------
// Pre-pass: fp32 [f][m] -> fp16 GRANULE-MAJOR hT[b][f8][m][8]. (round 6:
// coalesced staging worth 107->58 us; layout verified.)
// ---------------------------------------------------------------------------
__global__ __launch_bounds__(256) void convert_f16_kernel(
    const float* __restrict__ m1, const float* __restrict__ m2,
    u16* __restrict__ hT)
{
    __shared__ float tile[64 * M];   // 32 KB
    const int mat = blockIdx.x >> 6;
    const int b   = blockIdx.x & 63;
    const int f0  = blockIdx.y * 64;
    const float* src = (mat == 0 ? m1 : m2) + (size_t)b * MF + (size_t)f0 * M;
    const int tid = threadIdx.x;

    const float4* g = (const float4*)src;
    float4* s = (float4*)tile;
    #pragma unroll
    for (int i = 0; i < 8; ++i)
        s[tid + i * 256] = g[tid + i * 256];
    __syncthreads();

    const size_t obase = ((size_t)(mat * BS + b) * 32 + (f0 >> 3)) * 1024;
    #pragma unroll
    for (int it = 0; it < 4; ++it) {
        const int idx = it * 256 + tid;
        const int f8l = idx >> 7;
        const int m   = idx & 127;
        u16 hh[8] __attribute__((aligned(16)));
        #pragma unroll
        for (int j = 0; j < 8; ++j) {
            const float x = tile[(f8l * 8 + j) * M + m];  // 2 lanes/bank: free
            const _Float16 h = (_Float16)x;               // RNE
            hh[j] = __builtin_bit_cast(u16, h);
        }
        *(uint4*)&hT[obase + (size_t)idx * 8] = *(const uint4*)hh;
    }
}

// ---------------------------------------------------------------------------
// One block per (a, b-pair): pairs (a,b1),(a,b2=b1+1) share the A-tile.
// 4 waves; wave w = (pp=w>>1, c=w&1) computes a 128x64 region of pair pp.
//
// ROUND 9: B tiles have ZERO cross-wave LDS reuse (each B element staged to
// LDS was read back exactly once per block) -> B now loads DIRECT global->
// VGPR as MFMA fragments (the hT granule-major layout IS the fragment
// layout), prefetched one iteration ahead into named double-buffered regs.
// Only A (4x wave reuse) still goes through LDS. LDS traffic per block-iter
// drops 72 KB -> 40 KB (-44%); ds_writes 6 -> 2 per thread-iter; LDS block
// size 48 KB -> 16 KB. Barrier still only orders the A ds_writes; B global
// loads have a full MFMA phase (~1000+ cyc) to land before consumption.
// Budget: 128 AGPR acc + bc/bn 32 + af 16 + r0/r1 8 + addr ~20 < 256/wave.
// ---------------------------------------------------------------------------
__global__ __launch_bounds__(256, 2) void gram_hist_mfma(
    const u16* __restrict__ hT, float* __restrict__ out)
{
    __shared__ u16 lds[2 * 4096];   // 16 KB: A tiles only, double-buffered
    __shared__ float smin[4], smax[4];
    __shared__ int hist[2][8];

    const int tid  = threadIdx.x;
    const int lane = tid & 63;
    const int w    = tid >> 6;

    if (tid < 16) hist[tid >> 3][tid & 7] = 0;

    // Decode blockIdx.x -> (a, p) with per-a count ceil((64-a)/2).
    int p = blockIdx.x, a = 0;
    { int cnt = 32; while (p >= cnt) { p -= cnt; ++a; cnt = (64 - a + 1) >> 1; } }
    const int b1 = a + 2 * p;
    int b2 = b1 + 1;
    const bool b2valid = (b2 <= 63);
    if (!b2valid) b2 = b1;          // duplicate work, writes suppressed
    const int mat = blockIdx.y;

    const int pp = w >> 1;     // which pair (0: b1, 1: b2)
    const int c  = w & 1;      // which 64-col half
    const int l31   = lane & 31;
    const int lhalf = lane >> 5;

    // A staging source pointer (advance by 4096 u16 per chunk).
    const u16* pa = hT + (size_t)(mat * BS + a) * MF + tid * 8;
    const int d0 = tid * 8;            // A, first 256 granules
    const int d1 = (256 + tid) * 8;    // A, second

    // B fragment base pointer: per-lane address of frag (kk=0,t=0).
    // frag(kk,t) = pb + it*4096 + kk*2048 + t*256   (u16 units)
    // (derivation: ((kk*2+lhalf)*128 + c*64 + t*32 + l31)*8
    //            = kk*2048 + lhalf*1024 + c*512 + t*256 + l31*8)
    const int bsel = pp ? b2 : b1;
    const u16* pb = hT + (size_t)(mat * BS + bsel) * MF
                  + (size_t)(lhalf * 1024 + c * 512 + l31 * 8);

    f32x16 acc[4][2];
    #pragma unroll
    for (int ti = 0; ti < 4; ++ti)
        #pragma unroll
        for (int u = 0; u < 2; ++u)
            #pragma unroll
            for (int r = 0; r < 16; ++r) acc[ti][u][r] = 0.0f;

    f16x8 bc[2][2], bn[2][2];   // current / next B fragments [kk][u]

    // ---- prologue: A chunk 0 -> LDS, B frags chunk 0 -> regs ----
    uint4 r0 = *(const uint4*)(pa);
    uint4 r1 = *(const uint4*)(pa + 2048);
    #pragma unroll
    for (int kk = 0; kk < 2; ++kk)
        #pragma unroll
        for (int t = 0; t < 2; ++t)
            bc[kk][t] = *(const f16x8*)(pb + kk * 2048 + t * 256);
    *(uint4*)&lds[d0] = r0;
    *(uint4*)&lds[d1] = r1;
    __syncthreads();

    for (int it = 0; it < 8; ++it) {
        const int cur = (it & 1) * 4096;
        const int alt = cur ^ 4096;

        if (it < 7) {   // global->VGPR for chunk it+1 (latency hidden by MFMA)
            const int koff = (it + 1) * 4096;
            r0 = *(const uint4*)(pa + koff);
            r1 = *(const uint4*)(pa + koff + 2048);
            #pragma unroll
            for (int kk = 0; kk < 2; ++kk)
                #pragma unroll
                for (int t = 0; t < 2; ++t)
                    bn[kk][t] = *(const f16x8*)(pb + koff + kk * 2048 + t * 256);
        }

        #pragma unroll
        for (int kk = 0; kk < 2; ++kk) {
            const int kb = kk * 2 + lhalf;
            f16x8 af[4];
            #pragma unroll
            for (int t = 0; t < 4; ++t)
                af[t] = *(const f16x8*)&lds[cur + (kb * 128 + t * 32 + l31) * 8];
            #pragma unroll
            for (int ti = 0; ti < 4; ++ti)
                #pragma unroll
                for (int u = 0; u < 2; ++u)
                    acc[ti][u] = __builtin_amdgcn_mfma_f32_32x32x16_f16(af[ti], bc[kk][u], acc[ti][u], 0, 0, 0);
        }

        if (it < 7) {   // A VGPR->LDS (alt buffer); rotate B frag regs
            *(uint4*)&lds[alt + d0] = r0;
            *(uint4*)&lds[alt + d1] = r1;
            #pragma unroll
            for (int kk = 0; kk < 2; ++kk)
                #pragma unroll
                for (int t = 0; t < 2; ++t)
                    bc[kk][t] = bn[kk][t];
        }
        __syncthreads();   // orders A LDS writes (vmcnt drain lands free:
                           // B loads had the whole MFMA phase in flight)
    }

    // ---- epilogue: pair pp owned by waves (pp,c=0),(pp,c=1) ----
    float vmin = acc[0][0][0], vmax = vmin;
    #pragma unroll
    for (int ti = 0; ti < 4; ++ti)
        #pragma unroll
        for (int u = 0; u < 2; ++u)
            #pragma unroll
            for (int r = 0; r < 16; ++r) {
                vmin = fminf(vmin, acc[ti][u][r]);
                vmax = fmaxf(vmax, acc[ti][u][r]);
            }
    #pragma unroll
    for (int off = 1; off < 64; off <<= 1) {
        vmin = fminf(vmin, __shfl_xor(vmin, off, 64));
        vmax = fmaxf(vmax, __shfl_xor(vmax, off, 64));
    }
    if (lane == 0) { smin[w] = vmin; smax[w] = vmax; }
    __syncthreads();
    const float pmn = fminf(smin[pp * 2], smin[pp * 2 + 1]);
    const float pmx = fmaxf(smax[pp * 2], smax[pp * 2 + 1]);
    const float denom = (pmx > pmn) ? (pmx - pmn) : 1.0f;
    const float scale = 8.0f / denom;
    const float bias  = -pmn * scale;

    // per-thread packed histogram: 128 values -> 8-bit fields (<=128/bin)
    unsigned w0 = 0, w1 = 0;
    #pragma unroll
    for (int ti = 0; ti < 4; ++ti)
        #pragma unroll
        for (int u = 0; u < 2; ++u)
            #pragma unroll
            for (int r = 0; r < 16; ++r) {
                const float t = fmaf(acc[ti][u][r], scale, bias);
                int k = (int)t;          // t >= -eps; trunc == floor
                k = k > 7 ? 7 : k;
                const unsigned inc = 1u << ((k & 3) * 8);
                if (k < 4) w0 += inc; else w1 += inc;
            }
    unsigned e0 = (w0 & 0xFFu)         | (((w0 >> 8)  & 0xFFu) << 16);
    unsigned e1 = ((w0 >> 16) & 0xFFu) | (((w0 >> 24) & 0xFFu) << 16);
    unsigned e2 = (w1 & 0xFFu)         | (((w1 >> 8)  & 0xFFu) << 16);
    unsigned e3 = ((w1 >> 16) & 0xFFu) | (((w1 >> 24) & 0xFFu) << 16);
    #pragma unroll
    for (int off = 32; off > 0; off >>= 1) {
        e0 += __shfl_down(e0, off, 64);
        e1 += __shfl_down(e1, off, 64);
        e2 += __shfl_down(e2, off, 64);
        e3 += __shfl_down(e3, off, 64);
    }
    if (lane == 0) {
        atomicAdd(&hist[pp][0], (int)(e0 & 0xFFFFu)); atomicAdd(&hist[pp][1], (int)(e0 >> 16));
        atomicAdd(&hist[pp][2], (int)(e1 & 0xFFFFu)); atomicAdd(&hist[pp][3], (int)(e1 >> 16));
        atomicAdd(&hist[pp][4], (int)(e2 & 0xFFFFu)); atomicAdd(&hist[pp][5], (int)(e2 >> 16));
        atomicAdd(&hist[pp][6], (int)(e3 & 0xFFFFu)); atomicAdd(&hist[pp][7], (int)(e3 >> 16));
    }
    __syncthreads();

    // one wave per pair normalizes and writes both symmetric rows
    const int B = (pp == 0) ? b1 : b2;
    const bool valid = (pp == 0) || b2valid;
    if (valid && c == 0 && lane < 8) {
        float ss = 0.0f;
        #pragma unroll
        for (int k = 0; k < 8; ++k) {
            const float cc = (float)hist[pp][k];
            ss += cc * cc;
        }
        const float nrm = fmaxf(sqrtf(ss), 1e-12f);
        const float v = (float)hist[pp][lane] / nrm;
        out[((size_t)a * BS + B) * 16 + mat * 8 + lane] = v;
        if (a != B)
            out[((size_t)B * BS + a) * 16 + mat * 8 + lane] = v;
    }
}

extern "C" void kernel_launch(void* const* d_in, const int* in_sizes, int n_in,
                              void* d_out, int out_size, void* d_ws, size_t ws_size,
                              hipStream_t stream) {
    const float* m1 = (const float*)d_in[0];
    const float* m2 = (const float*)d_in[1];
    float* out = (float*)d_out;

    // Workspace: granule-major fp16 array, 2*64*128*256 u16 = 8.39 MB.
    u16* hT = (u16*)d_ws;

    convert_f16_kernel<<<dim3(128, 4), 256, 0, stream>>>(m1, m2, hT);
    gram_hist_mfma<<<dim3(NBP, 2), 256, 0, stream>>>(hT, out);
}